// Round 1
// baseline (38664.471 us; speedup 1.0000x reference)
//
#include <hip/hip_runtime.h>
#include <math.h>

// Shapes
#define NB   256   // batch N
#define TDIM 87
#define HD   128
#define H3   384
#define NCLS 43

__device__ __forceinline__ float sigmoidf_(float x){ return 1.0f/(1.0f + __expf(-x)); }
__device__ __forceinline__ float tanhf_(float x){ return 1.0f - 2.0f/(1.0f + __expf(2.0f*x)); }
__device__ __forceinline__ float lrelu_(float x){ return x > 0.f ? x : 0.01f*x; }

// ---------------- conv1 + relu + maxpool ----------------
// in: tce (256,87,21,50) NCHW; w1 (87,87,5,5); out pool1 (256,87,8,22)
__global__ __launch_bounds__(256) void k_conv1(const float* __restrict__ tce,
    const float* __restrict__ w1, const float* __restrict__ b1,
    float* __restrict__ pool1){
  const int n = blockIdx.x, oc = blockIdx.y;
  __shared__ float xs[21*52];
  __shared__ float ws[32];
  __shared__ float cv[17*48];
  const int tid = threadIdx.x;
  const int oh = tid/12, owc = (tid%12)*4;
  const bool act = tid < 204;                // 17 rows x 12 chunks of 4
  const float bias = b1[oc];
  float acc[4];
  #pragma unroll
  for (int j=0;j<4;j++) acc[j] = bias;
  const float* xin  = tce + (size_t)(n*TDIM)*1050;   // 21*50
  const float* wrow = w1  + (size_t)oc*TDIM*25;
  for (int ic=0; ic<TDIM; ++ic){
    for (int j=tid; j<1050; j+=256){ xs[(j/50)*52 + (j%50)] = xin[(size_t)ic*1050 + j]; }
    if (tid < 25) ws[tid] = wrow[ic*25 + tid];
    __syncthreads();
    if (act){
      float wreg[25];
      #pragma unroll
      for (int u=0;u<25;u++) wreg[u] = ws[u];
      #pragma unroll
      for (int r=0;r<5;r++){
        const float4* xr = (const float4*)&xs[(oh+r)*52 + owc];
        float4 v0 = xr[0], v1 = xr[1];
        float xv[8] = {v0.x,v0.y,v0.z,v0.w,v1.x,v1.y,v1.z,v1.w};
        #pragma unroll
        for (int c=0;c<5;c++){
          float w = wreg[r*5+c];
          #pragma unroll
          for (int j=0;j<4;j++) acc[j] = fmaf(w, xv[c+j], acc[j]);
        }
      }
    }
    __syncthreads();
  }
  if (act){
    #pragma unroll
    for (int j=0;j<4;j++){
      int ow = owc + j;
      if (ow < 46) cv[oh*48 + ow] = fmaxf(acc[j], 0.0f);
    }
  }
  __syncthreads();
  if (tid < 176){  // 8x22 pool outputs
    int ph = tid/22, pw = tid%22;
    float m = -1e30f;
    #pragma unroll
    for (int r=0;r<3;r++)
      #pragma unroll
      for (int c=0;c<3;c++)
        m = fmaxf(m, cv[(2*ph+r)*48 + (2*pw+c)]);
    pool1[((size_t)(n*TDIM+oc))*176 + tid] = m;
  }
}

// ---------------- conv2 + relu + maxpool -> cnn (256,87,8) ----------------
__global__ __launch_bounds__(128) void k_conv2(const float* __restrict__ pool1,
    const float* __restrict__ w2, const float* __restrict__ b2,
    float* __restrict__ cnn){
  const int n = blockIdx.x, oc = blockIdx.y;
  __shared__ float xs[176];
  __shared__ float ws[32];
  __shared__ float cv[72];
  const int tid = threadIdx.x;
  float a = b2[oc];
  const int oh = tid/18, ow = tid%18;   // valid if tid<72
  const float* xin = pool1 + (size_t)n*TDIM*176;
  const float* wr  = w2 + (size_t)oc*TDIM*25;
  for (int ic=0; ic<TDIM; ++ic){
    for (int j=tid; j<176; j+=128) xs[j] = xin[(size_t)ic*176 + j];
    if (tid < 25) ws[tid] = wr[ic*25 + tid];
    __syncthreads();
    if (tid < 72){
      #pragma unroll
      for (int r=0;r<5;r++)
        #pragma unroll
        for (int c=0;c<5;c++)
          a = fmaf(ws[r*5+c], xs[(oh+r)*22 + (ow+c)], a);
    }
    __syncthreads();
  }
  if (tid < 72) cv[tid] = fmaxf(a, 0.0f);
  __syncthreads();
  if (tid < 8){
    float m = -1e30f;
    #pragma unroll
    for (int r=0;r<3;r++)
      #pragma unroll
      for (int c=0;c<3;c++)
        m = fmaxf(m, cv[r*18 + (2*tid+c)]);
    cnn[((size_t)(n*TDIM+oc))*8 + tid] = m;
  }
}

// ---------------- utterance bi-GRU (one block per dir x batch-row) ----------------
// x_t = [te(50), cnn(8)]; weights register-stationary, K-split 2 across thread pairs.
__global__ __launch_bounds__(768,3) void k_utt(
    const float* __restrict__ te, const float* __restrict__ cnn,
    const float* __restrict__ wih_f, const float* __restrict__ whh_f,
    const float* __restrict__ bih_f, const float* __restrict__ bhh_f,
    const float* __restrict__ wih_b, const float* __restrict__ whh_b,
    const float* __restrict__ bih_b, const float* __restrict__ bhh_b,
    float* __restrict__ Hall){
  const int bx  = blockIdx.x;
  const int dir = bx & 1;
  const int n   = bx >> 1;
  const int tid = threadIdx.x;
  const int o   = tid >> 1, kh = tid & 1;
  const float* wih = dir ? wih_b : wih_f;
  const float* whh = dir ? whh_b : whh_f;
  const float* bih = dir ? bih_b : bih_f;
  const float* bhh = dir ? bhh_b : bhh_f;
  float wh[64], wi[32];
  { const float4* wp = (const float4*)(whh + (size_t)o*128 + kh*64);
    #pragma unroll
    for (int q=0;q<16;q++){ float4 v=wp[q]; wh[4*q]=v.x; wh[4*q+1]=v.y; wh[4*q+2]=v.z; wh[4*q+3]=v.w; } }
  #pragma unroll
  for (int k=0;k<32;k++){ int c = kh*32 + k; wi[k] = (c < 58) ? wih[(size_t)o*58 + c] : 0.f; }
  const float bI = bih[o], bH = bhh[o];
  __shared__ float h[128];
  __shared__ float xb[64];
  __shared__ float s_rz[256];
  __shared__ float gin_s[128];
  __shared__ float ghn_s[128];
  if (tid < 128) h[tid] = 0.f;
  if (tid < 64)  xb[tid] = 0.f;
  __syncthreads();
  for (int t=0;t<TDIM;++t){
    const int ttt = dir ? (TDIM-1-t) : t;
    if (tid < 50)      xb[tid] = te[((size_t)n*TDIM + ttt)*50 + tid];
    else if (tid < 58) xb[tid] = cnn[((size_t)n*TDIM + ttt)*8 + (tid - 50)];
    __syncthreads();
    float a0=0,a1=0,a2=0,a3=0;
    const float4* hp = (const float4*)&h[kh*64];
    #pragma unroll
    for (int q=0;q<16;q++){ float4 hv=hp[q];
      a0=fmaf(wh[4*q],hv.x,a0); a1=fmaf(wh[4*q+1],hv.y,a1);
      a2=fmaf(wh[4*q+2],hv.z,a2); a3=fmaf(wh[4*q+3],hv.w,a3); }
    float ah = (a0+a1)+(a2+a3);
    float c0=0,c1=0,c2=0,c3=0;
    const float4* xp = (const float4*)&xb[kh*32];
    #pragma unroll
    for (int q=0;q<8;q++){ float4 xv=xp[q];
      c0=fmaf(wi[4*q],xv.x,c0); c1=fmaf(wi[4*q+1],xv.y,c1);
      c2=fmaf(wi[4*q+2],xv.z,c2); c3=fmaf(wi[4*q+3],xv.w,c3); }
    float ai = (c0+c1)+(c2+c3);
    ah += __shfl_xor(ah, 1);
    ai += __shfl_xor(ai, 1);
    if (kh == 0){
      if (o < 256) s_rz[o] = ah + ai + bI + bH;
      else { gin_s[o-256] = ai + bI; ghn_s[o-256] = ah + bH; }
    }
    __syncthreads();
    if (tid < 128){
      float r  = sigmoidf_(s_rz[tid]);
      float z  = sigmoidf_(s_rz[128+tid]);
      float nn = tanhf_(gin_s[tid] + r*ghn_s[tid]);
      h[tid] = (1.f - z)*nn + z*h[tid];
    }
    __syncthreads();
  }
  if (tid < 128) Hall[(size_t)n*256 + dir*128 + tid] = h[tid];
}

// ---------------- prep: a_all = Hall @ w1.T, s_all = Hall . proj_w ----------------
__global__ __launch_bounds__(256) void k_prep(const float* __restrict__ Hall,
    const float* __restrict__ ctx_w1, const float* __restrict__ proj_w,
    float* __restrict__ a_all, float* __restrict__ s_all){
  const int i = blockIdx.x; const int tid = threadIdx.x;
  __shared__ float hr[256];
  __shared__ float red[2];
  hr[tid] = Hall[(size_t)i*256 + tid];
  __syncthreads();
  if (tid < 128){
    const float4* w  = (const float4*)(ctx_w1 + (size_t)tid*256);
    const float4* hp = (const float4*)hr;
    float a0=0,a1=0,a2=0,a3=0;
    #pragma unroll 8
    for (int q=0;q<64;q++){ float4 wv=w[q], hv=hp[q];
      a0=fmaf(wv.x,hv.x,a0); a1=fmaf(wv.y,hv.y,a1); a2=fmaf(wv.z,hv.z,a2); a3=fmaf(wv.w,hv.w,a3); }
    a_all[(size_t)i*128 + tid] = (a0+a1)+(a2+a3);
  } else {
    const int k = tid - 128;
    float p = hr[k]*proj_w[k] + hr[k+128]*proj_w[k+128];
    #pragma unroll
    for (int off=32; off; off>>=1) p += __shfl_xor(p, off);
    if ((tid & 63) == 0) red[(tid-128)>>6] = p;
  }
  __syncthreads();
  if (tid == 0) s_all[i] = red[0] + red[1];
}

// ---------------- ctx scan: 4 persistent blocks (F d=0,1 free-run; B d=0,1 consume) ----------------
__global__ __launch_bounds__(768,3) void k_ctx(
    const float* __restrict__ cg_wih_f, const float* __restrict__ cg_whh_f,
    const float* __restrict__ cg_bih_f, const float* __restrict__ cg_bhh_f,
    const float* __restrict__ cg_wih_b, const float* __restrict__ cg_whh_b,
    const float* __restrict__ cg_bih_b, const float* __restrict__ cg_bhh_b,
    const float* __restrict__ ctx_w2, const float* __restrict__ ctx_b2,
    const float* __restrict__ ctx_w3, const float* __restrict__ proj_b,
    const float* __restrict__ gx0,
    const float* __restrict__ a_all, const float* __restrict__ s_all,
    float* __restrict__ one_d_g, int* __restrict__ flags,
    float* __restrict__ feats){
  const int blk = blockIdx.x;
  const bool isF = blk < 2;
  const int d   = blk & 1;
  const int tid = threadIdx.x;
  const int o   = tid >> 1, kh = tid & 1;
  const float* whh = isF ? cg_whh_f : cg_whh_b;
  const float* wih = isF ? cg_wih_f : cg_wih_b;
  const float* bih = isF ? cg_bih_f : cg_bih_b;
  const float* bhh = isF ? cg_bhh_f : cg_bhh_b;
  float wh[64];
  { const float4* wp = (const float4*)(whh + (size_t)o*128 + kh*64);
    #pragma unroll
    for (int q=0;q<16;q++){ float4 v=wp[q]; wh[4*q]=v.x; wh[4*q+1]=v.y; wh[4*q+2]=v.z; wh[4*q+3]=v.w; } }
  const float bH = bhh[o];
  float wir=0,wiz=0,win=0,bir=0,biz=0,bin_=0;
  if (tid < 128){
    wir = wih[tid]; wiz = wih[128+tid]; win = wih[256+tid];
    bir = bih[tid]; biz = bih[128+tid]; bin_ = bih[256+tid];
  }
  const float pb = proj_b[0];
  __shared__ float h[128];
  __shared__ float s_rz[256];
  __shared__ float ghn_s[128];
  __shared__ float one_d_s[128];
  __shared__ float T_s[128];
  __shared__ float S_s[128];
  __shared__ float red_s[2];
  if (tid < 128) h[tid] = gx0[(size_t)((isF ? d : 2+d))*128 + tid];
  __syncthreads();
  for (int i=0;i<NB;++i){
    if (isF){
      // ---- attention: T = tanh(a + h@w2.T + b2); S = T@w3.T; one_d = softmax(S)*s + pb
      if (tid < 256){
        float a0=0,a1=0,a2=0,a3=0;
        const float4* w2p = (const float4*)(ctx_w2 + (size_t)o*128 + kh*64);
        const float4* hp  = (const float4*)&h[kh*64];
        #pragma unroll
        for (int q=0;q<16;q++){ float4 wv=w2p[q], hv=hp[q];
          a0=fmaf(wv.x,hv.x,a0); a1=fmaf(wv.y,hv.y,a1); a2=fmaf(wv.z,hv.z,a2); a3=fmaf(wv.w,hv.w,a3); }
        float p = (a0+a1)+(a2+a3);
        p += __shfl_xor(p, 1);
        if (kh == 0) T_s[o] = tanhf_(a_all[(size_t)i*128 + o] + p + ctx_b2[o]);
      }
      __syncthreads();
      if (tid < 256){
        float a0=0,a1=0,a2=0,a3=0;
        const float4* w3p = (const float4*)(ctx_w3 + (size_t)o*128 + kh*64);
        const float4* tp  = (const float4*)&T_s[kh*64];
        #pragma unroll
        for (int q=0;q<16;q++){ float4 wv=w3p[q], tv=tp[q];
          a0=fmaf(wv.x,tv.x,a0); a1=fmaf(wv.y,tv.y,a1); a2=fmaf(wv.z,tv.z,a2); a3=fmaf(wv.w,tv.w,a3); }
        float p = (a0+a1)+(a2+a3);
        p += __shfl_xor(p, 1);
        if (kh == 0) S_s[o] = p;
      }
      __syncthreads();
      if (tid < 64){
        float m = fmaxf(S_s[tid], S_s[tid+64]);
        #pragma unroll
        for (int off=32; off; off>>=1) m = fmaxf(m, __shfl_xor(m, off));
        if (tid == 0) red_s[0] = m;
      }
      __syncthreads();
      if (tid < 128) S_s[tid] = __expf(S_s[tid] - red_s[0]);
      __syncthreads();
      if (tid < 64){
        float s = S_s[tid] + S_s[tid+64];
        #pragma unroll
        for (int off=32; off; off>>=1) s += __shfl_xor(s, off);
        if (tid == 0) red_s[1] = s;
      }
      __syncthreads();
      if (tid < 128){
        float v = (S_s[tid] / red_s[1]) * s_all[i] + pb;
        one_d_s[tid] = v;
        __hip_atomic_store(&one_d_g[((size_t)d*NB + i)*128 + tid], v,
                           __ATOMIC_RELAXED, __HIP_MEMORY_SCOPE_AGENT);
      }
      __syncthreads();
      if (tid == 0){
        __threadfence();
        __hip_atomic_store(&flags[d], i+1, __ATOMIC_RELEASE, __HIP_MEMORY_SCOPE_AGENT);
      }
    } else {
      if (tid == 0){
        while (__hip_atomic_load(&flags[d], __ATOMIC_ACQUIRE, __HIP_MEMORY_SCOPE_AGENT) < i+1){
          __builtin_amdgcn_s_sleep(8);
        }
      }
      __syncthreads();
      if (tid < 128)
        one_d_s[tid] = __hip_atomic_load(&one_d_g[((size_t)d*NB + i)*128 + tid],
                                         __ATOMIC_RELAXED, __HIP_MEMORY_SCOPE_AGENT);
      __syncthreads();
    }
    // ---- inner GRU, 128 cells (F: t ascending; B: t descending)
    for (int tc=0; tc<128; ++tc){
      float a0=0,a1=0,a2=0,a3=0;
      const float4* hp = (const float4*)&h[kh*64];
      #pragma unroll
      for (int q=0;q<16;q++){ float4 hv=hp[q];
        a0=fmaf(wh[4*q],hv.x,a0); a1=fmaf(wh[4*q+1],hv.y,a1);
        a2=fmaf(wh[4*q+2],hv.z,a2); a3=fmaf(wh[4*q+3],hv.w,a3); }
      float ah = (a0+a1)+(a2+a3);
      ah += __shfl_xor(ah, 1);
      if (kh == 0){
        if (o < 256) s_rz[o] = ah + bH;
        else ghn_s[o-256] = ah + bH;
      }
      __syncthreads();
      if (tid < 128){
        float x  = one_d_s[isF ? tc : 127-tc];
        float r  = sigmoidf_(fmaf(x, wir, bir) + s_rz[tid]);
        float z  = sigmoidf_(fmaf(x, wiz, biz) + s_rz[128+tid]);
        float nn = tanhf_(fmaf(x, win, bin_) + r*ghn_s[tid]);
        h[tid] = (1.f - z)*nn + z*h[tid];
      }
      __syncthreads();
    }
    if (tid < 128)
      feats[(size_t)i*512 + (isF ? d*128 : 256 + d*128) + tid] = h[tid];
    __syncthreads();
  }
}

// ---------------- classifier ----------------
__global__ __launch_bounds__(256) void k_cls(const float* __restrict__ feats,
    const float* __restrict__ w1, const float* __restrict__ b1,
    const float* __restrict__ w2, const float* __restrict__ b2,
    const float* __restrict__ w3, const float* __restrict__ b3,
    float* __restrict__ out){
  const int n = blockIdx.x; const int tid = threadIdx.x;
  __shared__ float fr[512];
  __shared__ float h1s[256];
  __shared__ float h2s[128];
  fr[tid]       = feats[(size_t)n*512 + tid];
  fr[tid+256]   = feats[(size_t)n*512 + 256 + tid];
  __syncthreads();
  {
    const float4* w  = (const float4*)(w1 + (size_t)tid*512);
    const float4* fp = (const float4*)fr;
    float a0=0,a1=0,a2=0,a3=0;
    #pragma unroll 8
    for (int q=0;q<128;q++){ float4 wv=w[q], fv=fp[q];
      a0=fmaf(wv.x,fv.x,a0); a1=fmaf(wv.y,fv.y,a1); a2=fmaf(wv.z,fv.z,a2); a3=fmaf(wv.w,fv.w,a3); }
    h1s[tid] = lrelu_(b1[tid] + (a0+a1)+(a2+a3));
  }
  __syncthreads();
  if (tid < 128){
    const float4* w  = (const float4*)(w2 + (size_t)tid*256);
    const float4* fp = (const float4*)h1s;
    float a0=0,a1=0,a2=0,a3=0;
    #pragma unroll 8
    for (int q=0;q<64;q++){ float4 wv=w[q], fv=fp[q];
      a0=fmaf(wv.x,fv.x,a0); a1=fmaf(wv.y,fv.y,a1); a2=fmaf(wv.z,fv.z,a2); a3=fmaf(wv.w,fv.w,a3); }
    h2s[tid] = lrelu_(b2[tid] + (a0+a1)+(a2+a3));
  }
  __syncthreads();
  if (tid < NCLS){
    const float4* w  = (const float4*)(w3 + (size_t)tid*128);
    const float4* fp = (const float4*)h2s;
    float a0=0,a1=0,a2=0,a3=0;
    #pragma unroll 8
    for (int q=0;q<32;q++){ float4 wv=w[q], fv=fp[q];
      a0=fmaf(wv.x,fv.x,a0); a1=fmaf(wv.y,fv.y,a1); a2=fmaf(wv.z,fv.z,a2); a3=fmaf(wv.w,fv.w,a3); }
    out[(size_t)n*NCLS + tid] = b3[tid] + (a0+a1)+(a2+a3);
  }
}

// ---------------- workspace layout (bytes) ----------------
#define OFF_FLAGS  0u          //    64 B
#define OFF_SALL   512u        //  1024 B
#define OFF_AALL   2048u       // 131072 B
#define OFF_ONED   133632u     // 262144 B
#define OFF_HALL   395776u     // 262144 B
#define OFF_FEATS  657920u     // 524288 B
#define OFF_CNN    1182208u    // 712704 B
#define OFF_POOL1  1894912u    // 15681536 B  (total ~17.6 MB)

extern "C" void kernel_launch(void* const* d_in, const int* in_sizes, int n_in,
                              void* d_out, int out_size, void* d_ws, size_t ws_size,
                              hipStream_t stream){
  const float* te   = (const float*)d_in[0];
  const float* tce  = (const float*)d_in[1];
  const float* c1w  = (const float*)d_in[2];
  const float* c1b  = (const float*)d_in[3];
  const float* c2w  = (const float*)d_in[4];
  const float* c2b  = (const float*)d_in[5];
  const float* uwif = (const float*)d_in[6];
  const float* uwhf = (const float*)d_in[7];
  const float* ubif = (const float*)d_in[8];
  const float* ubhf = (const float*)d_in[9];
  const float* uwib = (const float*)d_in[10];
  const float* uwhb = (const float*)d_in[11];
  const float* ubib = (const float*)d_in[12];
  const float* ubhb = (const float*)d_in[13];
  const float* cw1  = (const float*)d_in[14];
  const float* cw2  = (const float*)d_in[15];
  const float* cb2  = (const float*)d_in[16];
  const float* cw3  = (const float*)d_in[17];
  const float* pw   = (const float*)d_in[18];
  const float* pbb  = (const float*)d_in[19];
  const float* gx0  = (const float*)d_in[20];
  const float* gwif = (const float*)d_in[21];
  const float* gwhf = (const float*)d_in[22];
  const float* gbif = (const float*)d_in[23];
  const float* gbhf = (const float*)d_in[24];
  const float* gwib = (const float*)d_in[25];
  const float* gwhb = (const float*)d_in[26];
  const float* gbib = (const float*)d_in[27];
  const float* gbhb = (const float*)d_in[28];
  const float* clw1 = (const float*)d_in[29];
  const float* clb1 = (const float*)d_in[30];
  const float* clw2 = (const float*)d_in[31];
  const float* clb2 = (const float*)d_in[32];
  const float* clw3 = (const float*)d_in[33];
  const float* clb3 = (const float*)d_in[34];
  float* out = (float*)d_out;
  char* ws = (char*)d_ws;
  int*   flags = (int*)  (ws + OFF_FLAGS);
  float* s_all = (float*)(ws + OFF_SALL);
  float* a_all = (float*)(ws + OFF_AALL);
  float* one_d = (float*)(ws + OFF_ONED);
  float* Hall  = (float*)(ws + OFF_HALL);
  float* feats = (float*)(ws + OFF_FEATS);
  float* cnn   = (float*)(ws + OFF_CNN);
  float* pool1 = (float*)(ws + OFF_POOL1);

  hipMemsetAsync(flags, 0, 64, stream);
  k_conv1<<<dim3(NB, TDIM), 256, 0, stream>>>(tce, c1w, c1b, pool1);
  k_conv2<<<dim3(NB, TDIM), 128, 0, stream>>>(pool1, c2w, c2b, cnn);
  k_utt<<<512, 768, 0, stream>>>(te, cnn, uwif, uwhf, ubif, ubhf,
                                 uwib, uwhb, ubib, ubhb, Hall);
  k_prep<<<NB, 256, 0, stream>>>(Hall, cw1, pw, a_all, s_all);
  k_ctx<<<4, 768, 0, stream>>>(gwif, gwhf, gbif, gbhf, gwib, gwhb, gbib, gbhb,
                               cw2, cb2, cw3, pbb, gx0, a_all, s_all,
                               one_d, flags, feats);
  k_cls<<<NB, 256, 0, stream>>>(feats, clw1, clb1, clw2, clb2, clw3, clb3, out);
}

// Round 2
// 38198.267 us; speedup vs baseline: 1.0122x; 1.0122x over previous
//
#include <hip/hip_runtime.h>
#include <math.h>

// Shapes
#define NB   256   // batch N
#define TDIM 87
#define HD   128
#define H3   384
#define NCLS 43

__device__ __forceinline__ float sigmoidf_(float x){ return 1.0f/(1.0f + __expf(-x)); }
__device__ __forceinline__ float tanhf_(float x){ return 1.0f - 2.0f/(1.0f + __expf(2.0f*x)); }
__device__ __forceinline__ float lrelu_(float x){ return x > 0.f ? x : 0.01f*x; }

// ---------------- conv1 + relu + maxpool ----------------
// in: tce (256,87,21,50) NCHW; w1 (87,87,5,5); out pool1 (256,87,8,22)
__global__ __launch_bounds__(256) void k_conv1(const float* __restrict__ tce,
    const float* __restrict__ w1, const float* __restrict__ b1,
    float* __restrict__ pool1){
  const int n = blockIdx.x, oc = blockIdx.y;
  __shared__ float xs[21*52];
  __shared__ float ws[32];
  __shared__ float cv[17*48];
  const int tid = threadIdx.x;
  const int oh = tid/12, owc = (tid%12)*4;
  const bool act = tid < 204;                // 17 rows x 12 chunks of 4
  const float bias = b1[oc];
  float acc[4];
  #pragma unroll
  for (int j=0;j<4;j++) acc[j] = bias;
  const float* xin  = tce + (size_t)(n*TDIM)*1050;   // 21*50
  const float* wrow = w1  + (size_t)oc*TDIM*25;
  for (int ic=0; ic<TDIM; ++ic){
    for (int j=tid; j<1050; j+=256){ xs[(j/50)*52 + (j%50)] = xin[(size_t)ic*1050 + j]; }
    if (tid < 25) ws[tid] = wrow[ic*25 + tid];
    __syncthreads();
    if (act){
      float wreg[25];
      #pragma unroll
      for (int u=0;u<25;u++) wreg[u] = ws[u];
      #pragma unroll
      for (int r=0;r<5;r++){
        const float4* xr = (const float4*)&xs[(oh+r)*52 + owc];
        float4 v0 = xr[0], v1 = xr[1];
        float xv[8] = {v0.x,v0.y,v0.z,v0.w,v1.x,v1.y,v1.z,v1.w};
        #pragma unroll
        for (int c=0;c<5;c++){
          float w = wreg[r*5+c];
          #pragma unroll
          for (int j=0;j<4;j++) acc[j] = fmaf(w, xv[c+j], acc[j]);
        }
      }
    }
    __syncthreads();
  }
  if (act){
    #pragma unroll
    for (int j=0;j<4;j++){
      int ow = owc + j;
      if (ow < 46) cv[oh*48 + ow] = fmaxf(acc[j], 0.0f);
    }
  }
  __syncthreads();
  if (tid < 176){  // 8x22 pool outputs
    int ph = tid/22, pw = tid%22;
    float m = -1e30f;
    #pragma unroll
    for (int r=0;r<3;r++)
      #pragma unroll
      for (int c=0;c<3;c++)
        m = fmaxf(m, cv[(2*ph+r)*48 + (2*pw+c)]);
    pool1[((size_t)(n*TDIM+oc))*176 + tid] = m;
  }
}

// ---------------- conv2 + relu + maxpool -> cnn (256,87,8) ----------------
__global__ __launch_bounds__(128) void k_conv2(const float* __restrict__ pool1,
    const float* __restrict__ w2, const float* __restrict__ b2,
    float* __restrict__ cnn){
  const int n = blockIdx.x, oc = blockIdx.y;
  __shared__ float xs[176];
  __shared__ float ws[32];
  __shared__ float cv[72];
  const int tid = threadIdx.x;
  float a = b2[oc];
  const int oh = tid/18, ow = tid%18;   // valid if tid<72
  const float* xin = pool1 + (size_t)n*TDIM*176;
  const float* wr  = w2 + (size_t)oc*TDIM*25;
  for (int ic=0; ic<TDIM; ++ic){
    for (int j=tid; j<176; j+=128) xs[j] = xin[(size_t)ic*176 + j];
    if (tid < 25) ws[tid] = wr[ic*25 + tid];
    __syncthreads();
    if (tid < 72){
      #pragma unroll
      for (int r=0;r<5;r++)
        #pragma unroll
        for (int c=0;c<5;c++)
          a = fmaf(ws[r*5+c], xs[(oh+r)*22 + (ow+c)], a);
    }
    __syncthreads();
  }
  if (tid < 72) cv[tid] = fmaxf(a, 0.0f);
  __syncthreads();
  if (tid < 8){
    float m = -1e30f;
    #pragma unroll
    for (int r=0;r<3;r++)
      #pragma unroll
      for (int c=0;c<3;c++)
        m = fmaxf(m, cv[r*18 + (2*tid+c)]);
    cnn[((size_t)(n*TDIM+oc))*8 + tid] = m;
  }
}

// ---------------- utterance bi-GRU (one block per dir x batch-row) ----------------
__global__ __launch_bounds__(768,3) void k_utt(
    const float* __restrict__ te, const float* __restrict__ cnn,
    const float* __restrict__ wih_f, const float* __restrict__ whh_f,
    const float* __restrict__ bih_f, const float* __restrict__ bhh_f,
    const float* __restrict__ wih_b, const float* __restrict__ whh_b,
    const float* __restrict__ bih_b, const float* __restrict__ bhh_b,
    float* __restrict__ Hall){
  const int bx  = blockIdx.x;
  const int dir = bx & 1;
  const int n   = bx >> 1;
  const int tid = threadIdx.x;
  const int o   = tid >> 1, kh = tid & 1;
  const float* wih = dir ? wih_b : wih_f;
  const float* whh = dir ? whh_b : whh_f;
  const float* bih = dir ? bih_b : bih_f;
  const float* bhh = dir ? bhh_b : bhh_f;
  float wh[64], wi[32];
  { const float4* wp = (const float4*)(whh + (size_t)o*128 + kh*64);
    #pragma unroll
    for (int q=0;q<16;q++){ float4 v=wp[q]; wh[4*q]=v.x; wh[4*q+1]=v.y; wh[4*q+2]=v.z; wh[4*q+3]=v.w; } }
  #pragma unroll
  for (int k=0;k<32;k++){ int c = kh*32 + k; wi[k] = (c < 58) ? wih[(size_t)o*58 + c] : 0.f; }
  const float bI = bih[o], bH = bhh[o];
  __shared__ float h[128];
  __shared__ float xb[64];
  __shared__ float s_rz[256];
  __shared__ float gin_s[128];
  __shared__ float ghn_s[128];
  if (tid < 128) h[tid] = 0.f;
  if (tid < 64)  xb[tid] = 0.f;
  __syncthreads();
  for (int t=0;t<TDIM;++t){
    const int ttt = dir ? (TDIM-1-t) : t;
    if (tid < 50)      xb[tid] = te[((size_t)n*TDIM + ttt)*50 + tid];
    else if (tid < 58) xb[tid] = cnn[((size_t)n*TDIM + ttt)*8 + (tid - 50)];
    __syncthreads();
    float a0=0,a1=0,a2=0,a3=0;
    const float4* hp = (const float4*)&h[kh*64];
    #pragma unroll
    for (int q=0;q<16;q++){ float4 hv=hp[q];
      a0=fmaf(wh[4*q],hv.x,a0); a1=fmaf(wh[4*q+1],hv.y,a1);
      a2=fmaf(wh[4*q+2],hv.z,a2); a3=fmaf(wh[4*q+3],hv.w,a3); }
    float ah = (a0+a1)+(a2+a3);
    float c0=0,c1=0,c2=0,c3=0;
    const float4* xp = (const float4*)&xb[kh*32];
    #pragma unroll
    for (int q=0;q<8;q++){ float4 xv=xp[q];
      c0=fmaf(wi[4*q],xv.x,c0); c1=fmaf(wi[4*q+1],xv.y,c1);
      c2=fmaf(wi[4*q+2],xv.z,c2); c3=fmaf(wi[4*q+3],xv.w,c3); }
    float ai = (c0+c1)+(c2+c3);
    ah += __shfl_xor(ah, 1);
    ai += __shfl_xor(ai, 1);
    if (kh == 0){
      if (o < 256) s_rz[o] = ah + ai + bI + bH;
      else { gin_s[o-256] = ai + bI; ghn_s[o-256] = ah + bH; }
    }
    __syncthreads();
    if (tid < 128){
      float r  = sigmoidf_(s_rz[tid]);
      float z  = sigmoidf_(s_rz[128+tid]);
      float nn = tanhf_(gin_s[tid] + r*ghn_s[tid]);
      h[tid] = (1.f - z)*nn + z*h[tid];
    }
    __syncthreads();
  }
  if (tid < 128) Hall[(size_t)n*256 + dir*128 + tid] = h[tid];
}

// ---------------- prep: a_all = Hall @ w1.T, s_all = Hall . proj_w ----------------
__global__ __launch_bounds__(256) void k_prep(const float* __restrict__ Hall,
    const float* __restrict__ ctx_w1, const float* __restrict__ proj_w,
    float* __restrict__ a_all, float* __restrict__ s_all){
  const int i = blockIdx.x; const int tid = threadIdx.x;
  __shared__ float hr[256];
  __shared__ float red[2];
  hr[tid] = Hall[(size_t)i*256 + tid];
  __syncthreads();
  if (tid < 128){
    const float4* w  = (const float4*)(ctx_w1 + (size_t)tid*256);
    const float4* hp = (const float4*)hr;
    float a0=0,a1=0,a2=0,a3=0;
    #pragma unroll 8
    for (int q=0;q<64;q++){ float4 wv=w[q], hv=hp[q];
      a0=fmaf(wv.x,hv.x,a0); a1=fmaf(wv.y,hv.y,a1); a2=fmaf(wv.z,hv.z,a2); a3=fmaf(wv.w,hv.w,a3); }
    a_all[(size_t)i*128 + tid] = (a0+a1)+(a2+a3);
  } else {
    const int k = tid - 128;
    float p = hr[k]*proj_w[k] + hr[k+128]*proj_w[k+128];
    #pragma unroll
    for (int off=32; off; off>>=1) p += __shfl_xor(p, off);
    if ((tid & 63) == 0) red[(tid-128)>>6] = p;
  }
  __syncthreads();
  if (tid == 0) s_all[i] = red[0] + red[1];
}

// ---------------- ctx scan v2: 4 persistent blocks, 256 threads, register-stationary weights ----------------
// Thread (p = tid>>2 in [0,64), kq = tid&3 in [0,4)): owns outputs {p, p+64} for all 3 gates,
// K-quarter kq (32 of 128 h-dims). Quad shfl_xor reduce -> gates complete in kq==0 threads ->
// in-register nonlinearity + h update (h_old in regs). ONE barrier per cell.
// h in LDS padded: chunk c (32 floats) at hl[c*36] -> 4 read addresses hit banks 0/4/8/12 (conflict-free).
__global__ __launch_bounds__(256,1) void k_ctx(
    const float* __restrict__ cg_wih_f, const float* __restrict__ cg_whh_f,
    const float* __restrict__ cg_bih_f, const float* __restrict__ cg_bhh_f,
    const float* __restrict__ cg_wih_b, const float* __restrict__ cg_whh_b,
    const float* __restrict__ cg_bih_b, const float* __restrict__ cg_bhh_b,
    const float* __restrict__ ctx_w2, const float* __restrict__ ctx_b2,
    const float* __restrict__ ctx_w3, const float* __restrict__ proj_b,
    const float* __restrict__ gx0,
    const float* __restrict__ a_all, const float* __restrict__ s_all,
    float* __restrict__ one_d_g, int* __restrict__ flags,
    float* __restrict__ feats){
  const int blk = blockIdx.x;
  const bool isF = blk < 2;
  const int d   = blk & 1;
  const int tid = threadIdx.x;
  const int p   = tid >> 2;      // output pair index
  const int kq  = tid & 3;       // K-quarter
  const float* whh = isF ? cg_whh_f : cg_whh_b;
  const float* wih = isF ? cg_wih_f : cg_wih_b;
  const float* bih = isF ? cg_bih_f : cg_bih_b;
  const float* bhh = isF ? cg_bhh_f : cg_bhh_b;

  // ---- stationary weights in registers: 2 outputs x 3 gates x 32 K = 192 floats
  float wA[3][32], wB[3][32];
  #pragma unroll
  for (int g=0; g<3; ++g){
    const float4* ra = (const float4*)(whh + ((size_t)(g*128 + p))*128 + kq*32);
    const float4* rb = (const float4*)(whh + ((size_t)(g*128 + p + 64))*128 + kq*32);
    #pragma unroll
    for (int q=0;q<8;q++){
      float4 v = ra[q];
      wA[g][4*q]=v.x; wA[g][4*q+1]=v.y; wA[g][4*q+2]=v.z; wA[g][4*q+3]=v.w;
      float4 u = rb[q];
      wB[g][4*q]=u.x; wB[g][4*q+1]=u.y; wB[g][4*q+2]=u.z; wB[g][4*q+3]=u.w;
    }
  }
  const float wiA0 = wih[p],      wiA1 = wih[128+p],  wiA2 = wih[256+p];
  const float wiB0 = wih[64+p],   wiB1 = wih[192+p],  wiB2 = wih[320+p];
  const float bA0 = bih[p]     + bhh[p];
  const float bA1 = bih[128+p] + bhh[128+p];
  const float bA2 = bih[256+p];
  const float bhnA = bhh[256+p];
  const float bB0 = bih[64+p]  + bhh[64+p];
  const float bB1 = bih[192+p] + bhh[192+p];
  const float bB2 = bih[320+p];
  const float bhnB = bhh[320+p];
  const float pb = proj_b[0];

  __shared__ float hl[144];        // 4 chunks of 32 floats, stride 36 (pad 4)
  __shared__ float one_d_s[128];
  __shared__ float T_s[128];
  __shared__ float S_s[128];
  __shared__ float red_s[2];

  const float* gsrc = gx0 + (size_t)((isF ? 0 : 2) + d)*128;
  float hmA = 0.f, hmB = 0.f;
  if (tid < 128) hl[(tid>>5)*36 + (tid&31)] = gsrc[tid];
  if (kq == 0){ hmA = gsrc[p]; hmB = gsrc[p+64]; }
  __syncthreads();

  const int chA = (p>>5)*36 + (p&31);
  const int chB = chA + 72;

  for (int i=0;i<NB;++i){
    if (isF){
      const int o = tid >> 1, k2 = tid & 1;
      // ---- T = tanh(a_all + h@w2.T + b2)
      {
        const float4* w2p = (const float4*)(ctx_w2 + (size_t)o*128 + k2*64);
        const float4* hA  = (const float4*)&hl[(2*k2)*36];
        const float4* hB  = (const float4*)&hl[(2*k2+1)*36];
        float a0=0,a1=0,a2=0,a3=0;
        #pragma unroll
        for (int q=0;q<8;q++){ float4 wv=w2p[q], hv=hA[q];
          a0=fmaf(wv.x,hv.x,a0); a1=fmaf(wv.y,hv.y,a1); a2=fmaf(wv.z,hv.z,a2); a3=fmaf(wv.w,hv.w,a3); }
        #pragma unroll
        for (int q=0;q<8;q++){ float4 wv=w2p[8+q], hv=hB[q];
          a0=fmaf(wv.x,hv.x,a0); a1=fmaf(wv.y,hv.y,a1); a2=fmaf(wv.z,hv.z,a2); a3=fmaf(wv.w,hv.w,a3); }
        float s = (a0+a1)+(a2+a3);
        s += __shfl_xor(s, 1);
        if (k2 == 0) T_s[o] = tanhf_(a_all[(size_t)i*128 + o] + s + ctx_b2[o]);
      }
      __syncthreads();
      // ---- S = T@w3.T
      {
        const float4* w3p = (const float4*)(ctx_w3 + (size_t)o*128 + k2*64);
        const float4* tp  = (const float4*)&T_s[k2*64];
        float a0=0,a1=0,a2=0,a3=0;
        #pragma unroll
        for (int q=0;q<16;q++){ float4 wv=w3p[q], tv=tp[q];
          a0=fmaf(wv.x,tv.x,a0); a1=fmaf(wv.y,tv.y,a1); a2=fmaf(wv.z,tv.z,a2); a3=fmaf(wv.w,tv.w,a3); }
        float s = (a0+a1)+(a2+a3);
        s += __shfl_xor(s, 1);
        if (k2 == 0) S_s[o] = s;
      }
      __syncthreads();
      if (tid < 64){
        float m = fmaxf(S_s[tid], S_s[tid+64]);
        #pragma unroll
        for (int off=32; off; off>>=1) m = fmaxf(m, __shfl_xor(m, off));
        if (tid == 0) red_s[0] = m;
      }
      __syncthreads();
      if (tid < 128) S_s[tid] = __expf(S_s[tid] - red_s[0]);
      __syncthreads();
      if (tid < 64){
        float s = S_s[tid] + S_s[tid+64];
        #pragma unroll
        for (int off=32; off; off>>=1) s += __shfl_xor(s, off);
        if (tid == 0) red_s[1] = s;
      }
      __syncthreads();
      if (tid < 128){
        float v = (S_s[tid] / red_s[1]) * s_all[i] + pb;
        one_d_s[tid] = v;
        __hip_atomic_store(&one_d_g[((size_t)d*NB + i)*128 + tid], v,
                           __ATOMIC_RELAXED, __HIP_MEMORY_SCOPE_AGENT);
      }
      __syncthreads();
      if (tid == 0){
        __threadfence();
        __hip_atomic_store(&flags[d], i+1, __ATOMIC_RELEASE, __HIP_MEMORY_SCOPE_AGENT);
      }
    } else {
      if (tid == 0){
        while (__hip_atomic_load(&flags[d], __ATOMIC_ACQUIRE, __HIP_MEMORY_SCOPE_AGENT) < i+1){
          __builtin_amdgcn_s_sleep(8);
        }
      }
      __syncthreads();
      if (tid < 128)
        one_d_s[tid] = __hip_atomic_load(&one_d_g[((size_t)d*NB + i)*128 + tid],
                                         __ATOMIC_RELAXED, __HIP_MEMORY_SCOPE_AGENT);
      __syncthreads();
    }
    // ---- inner GRU, 128 cells, ONE barrier each
    for (int tc=0; tc<128; ++tc){
      const float4* hp = (const float4*)&hl[kq*36];
      float arA=0,azA=0,anA=0,arB=0,azB=0,anB=0;
      #pragma unroll
      for (int q=0;q<8;q++){
        float4 hv = hp[q];
        arA=fmaf(wA[0][4*q],hv.x,arA); arA=fmaf(wA[0][4*q+1],hv.y,arA); arA=fmaf(wA[0][4*q+2],hv.z,arA); arA=fmaf(wA[0][4*q+3],hv.w,arA);
        azA=fmaf(wA[1][4*q],hv.x,azA); azA=fmaf(wA[1][4*q+1],hv.y,azA); azA=fmaf(wA[1][4*q+2],hv.z,azA); azA=fmaf(wA[1][4*q+3],hv.w,azA);
        anA=fmaf(wA[2][4*q],hv.x,anA); anA=fmaf(wA[2][4*q+1],hv.y,anA); anA=fmaf(wA[2][4*q+2],hv.z,anA); anA=fmaf(wA[2][4*q+3],hv.w,anA);
        arB=fmaf(wB[0][4*q],hv.x,arB); arB=fmaf(wB[0][4*q+1],hv.y,arB); arB=fmaf(wB[0][4*q+2],hv.z,arB); arB=fmaf(wB[0][4*q+3],hv.w,arB);
        azB=fmaf(wB[1][4*q],hv.x,azB); azB=fmaf(wB[1][4*q+1],hv.y,azB); azB=fmaf(wB[1][4*q+2],hv.z,azB); azB=fmaf(wB[1][4*q+3],hv.w,azB);
        anB=fmaf(wB[2][4*q],hv.x,anB); anB=fmaf(wB[2][4*q+1],hv.y,anB); anB=fmaf(wB[2][4*q+2],hv.z,anB); anB=fmaf(wB[2][4*q+3],hv.w,anB);
      }
      arA += __shfl_xor(arA,1); arA += __shfl_xor(arA,2);
      azA += __shfl_xor(azA,1); azA += __shfl_xor(azA,2);
      anA += __shfl_xor(anA,1); anA += __shfl_xor(anA,2);
      arB += __shfl_xor(arB,1); arB += __shfl_xor(arB,2);
      azB += __shfl_xor(azB,1); azB += __shfl_xor(azB,2);
      anB += __shfl_xor(anB,1); anB += __shfl_xor(anB,2);
      if (kq == 0){
        float x = one_d_s[isF ? tc : 127-tc];
        float r  = sigmoidf_(fmaf(x, wiA0, bA0) + arA);
        float z  = sigmoidf_(fmaf(x, wiA1, bA1) + azA);
        float nn = tanhf_(fmaf(x, wiA2, bA2) + r*(anA + bhnA));
        hmA = (1.f - z)*nn + z*hmA;
        hl[chA] = hmA;
        r  = sigmoidf_(fmaf(x, wiB0, bB0) + arB);
        z  = sigmoidf_(fmaf(x, wiB1, bB1) + azB);
        nn = tanhf_(fmaf(x, wiB2, bB2) + r*(anB + bhnB));
        hmB = (1.f - z)*nn + z*hmB;
        hl[chB] = hmB;
      }
      __syncthreads();
    }
    if (kq == 0){
      const int off = isF ? d*128 : 256 + d*128;
      feats[(size_t)i*512 + off + p]      = hmA;
      feats[(size_t)i*512 + off + p + 64] = hmB;
    }
    __syncthreads();
  }
}

// ---------------- classifier ----------------
__global__ __launch_bounds__(256) void k_cls(const float* __restrict__ feats,
    const float* __restrict__ w1, const float* __restrict__ b1,
    const float* __restrict__ w2, const float* __restrict__ b2,
    const float* __restrict__ w3, const float* __restrict__ b3,
    float* __restrict__ out){
  const int n = blockIdx.x; const int tid = threadIdx.x;
  __shared__ float fr[512];
  __shared__ float h1s[256];
  __shared__ float h2s[128];
  fr[tid]       = feats[(size_t)n*512 + tid];
  fr[tid+256]   = feats[(size_t)n*512 + 256 + tid];
  __syncthreads();
  {
    const float4* w  = (const float4*)(w1 + (size_t)tid*512);
    const float4* fp = (const float4*)fr;
    float a0=0,a1=0,a2=0,a3=0;
    #pragma unroll 8
    for (int q=0;q<128;q++){ float4 wv=w[q], fv=fp[q];
      a0=fmaf(wv.x,fv.x,a0); a1=fmaf(wv.y,fv.y,a1); a2=fmaf(wv.z,fv.z,a2); a3=fmaf(wv.w,fv.w,a3); }
    h1s[tid] = lrelu_(b1[tid] + (a0+a1)+(a2+a3));
  }
  __syncthreads();
  if (tid < 128){
    const float4* w  = (const float4*)(w2 + (size_t)tid*256);
    const float4* fp = (const float4*)h1s;
    float a0=0,a1=0,a2=0,a3=0;
    #pragma unroll 8
    for (int q=0;q<64;q++){ float4 wv=w[q], fv=fp[q];
      a0=fmaf(wv.x,fv.x,a0); a1=fmaf(wv.y,fv.y,a1); a2=fmaf(wv.z,fv.z,a2); a3=fmaf(wv.w,fv.w,a3); }
    h2s[tid] = lrelu_(b2[tid] + (a0+a1)+(a2+a3));
  }
  __syncthreads();
  if (tid < NCLS){
    const float4* w  = (const float4*)(w3 + (size_t)tid*128);
    const float4* fp = (const float4*)h2s;
    float a0=0,a1=0,a2=0,a3=0;
    #pragma unroll 8
    for (int q=0;q<32;q++){ float4 wv=w[q], fv=fp[q];
      a0=fmaf(wv.x,fv.x,a0); a1=fmaf(wv.y,fv.y,a1); a2=fmaf(wv.z,fv.z,a2); a3=fmaf(wv.w,fv.w,a3); }
    out[(size_t)n*NCLS + tid] = b3[tid] + (a0+a1)+(a2+a3);
  }
}

// ---------------- workspace layout (bytes) ----------------
#define OFF_FLAGS  0u          //    64 B
#define OFF_SALL   512u        //  1024 B
#define OFF_AALL   2048u       // 131072 B
#define OFF_ONED   133632u     // 262144 B
#define OFF_HALL   395776u     // 262144 B
#define OFF_FEATS  657920u     // 524288 B
#define OFF_CNN    1182208u    // 712704 B
#define OFF_POOL1  1894912u    // 15681536 B  (total ~17.6 MB)

extern "C" void kernel_launch(void* const* d_in, const int* in_sizes, int n_in,
                              void* d_out, int out_size, void* d_ws, size_t ws_size,
                              hipStream_t stream){
  const float* te   = (const float*)d_in[0];
  const float* tce  = (const float*)d_in[1];
  const float* c1w  = (const float*)d_in[2];
  const float* c1b  = (const float*)d_in[3];
  const float* c2w  = (const float*)d_in[4];
  const float* c2b  = (const float*)d_in[5];
  const float* uwif = (const float*)d_in[6];
  const float* uwhf = (const float*)d_in[7];
  const float* ubif = (const float*)d_in[8];
  const float* ubhf = (const float*)d_in[9];
  const float* uwib = (const float*)d_in[10];
  const float* uwhb = (const float*)d_in[11];
  const float* ubib = (const float*)d_in[12];
  const float* ubhb = (const float*)d_in[13];
  const float* cw1  = (const float*)d_in[14];
  const float* cw2  = (const float*)d_in[15];
  const float* cb2  = (const float*)d_in[16];
  const float* cw3  = (const float*)d_in[17];
  const float* pw   = (const float*)d_in[18];
  const float* pbb  = (const float*)d_in[19];
  const float* gx0  = (const float*)d_in[20];
  const float* gwif = (const float*)d_in[21];
  const float* gwhf = (const float*)d_in[22];
  const float* gbif = (const float*)d_in[23];
  const float* gbhf = (const float*)d_in[24];
  const float* gwib = (const float*)d_in[25];
  const float* gwhb = (const float*)d_in[26];
  const float* gbib = (const float*)d_in[27];
  const float* gbhb = (const float*)d_in[28];
  const float* clw1 = (const float*)d_in[29];
  const float* clb1 = (const float*)d_in[30];
  const float* clw2 = (const float*)d_in[31];
  const float* clb2 = (const float*)d_in[32];
  const float* clw3 = (const float*)d_in[33];
  const float* clb3 = (const float*)d_in[34];
  float* out = (float*)d_out;
  char* ws = (char*)d_ws;
  int*   flags = (int*)  (ws + OFF_FLAGS);
  float* s_all = (float*)(ws + OFF_SALL);
  float* a_all = (float*)(ws + OFF_AALL);
  float* one_d = (float*)(ws + OFF_ONED);
  float* Hall  = (float*)(ws + OFF_HALL);
  float* feats = (float*)(ws + OFF_FEATS);
  float* cnn   = (float*)(ws + OFF_CNN);
  float* pool1 = (float*)(ws + OFF_POOL1);

  hipMemsetAsync(flags, 0, 64, stream);
  k_conv1<<<dim3(NB, TDIM), 256, 0, stream>>>(tce, c1w, c1b, pool1);
  k_conv2<<<dim3(NB, TDIM), 128, 0, stream>>>(pool1, c2w, c2b, cnn);
  k_utt<<<512, 768, 0, stream>>>(te, cnn, uwif, uwhf, ubif, ubhf,
                                 uwib, uwhb, ubib, ubhb, Hall);
  k_prep<<<NB, 256, 0, stream>>>(Hall, cw1, pw, a_all, s_all);
  k_ctx<<<4, 256, 0, stream>>>(gwif, gwhf, gbif, gbhf, gwib, gwhb, gbib, gbhb,
                               cw2, cb2, cw3, pbb, gx0, a_all, s_all,
                               one_d, flags, feats);
  k_cls<<<NB, 256, 0, stream>>>(feats, clw1, clb1, clw2, clb2, clw3, clb3, out);
}